// Round 4
// baseline (192.371 us; speedup 1.0000x reference)
//
#include <hip/hip_runtime.h>

// StateSpaceDiffusionModel — MFMA formulation, round 6: fine-grained
// producer/consumer, 5 waves/block, SC=1 chunk per step.
//
//   c_m  = S·u_m                    (parallel; consumer waves)
//   p_{m+1} = A·p_m + c_m           (A = S·W dense; serial; wave0 only)
//   y_m  = G'·p_m + G2S·u_m         (G' = G1 + G2·A, G2S = G2·S; consumers)
//
// Round-3 post-mortem: SC=4 super-steps amplified barrier skew (wave0's 4
// serial LDS round-trips per step), consumers duplicated ALL u conversion
// (16 cvt_split8/wave/step), and 123KB LDS forced 1 block/CU (2 passes).
// This round: SC=1 (wave0 step ~950cy), one mt-tile per consumer wave
// (18 MFMA + 2 cvt_split8 each), LDS 69.6KB -> 2 blocks/CU in ONE pass,
// 10 waves/CU so the co-resident block hides wave0's serial stalls.
//
// Pipeline (step s = 0..33, barrier per step, lgkm-only drain):
//   wave0  (1<=s<=32): publish pre-state p_{s-1} -> pring[(s-1)&1];
//                      r = A·p + cring[(s-1)&1]; RT -> new p frags.
//   waves1-4 (s<32):   cvt u_s, prefetch u_{s+1}, c_s[mt] -> cring[s&1],
//                      yu_s[mt] = G2S·u (regs, parity yuA/yuB);
//            (s>=2):   y_{s-2}[mt] = yu_{s-2} + G'·p_{s-2} (pring[s&1]).
// Numerics identical to round 3 (3-term hi/lo data path, 4-term A) -> same absmax.
//
// mfma_f32_16x16x32_bf16 layouts (m89/m120):
//   A[m][k]: m=lane&15, k=(lane>>4)*8+j (+32*tk)
//   B[k][n]: k=(lane>>4)*8+j (+32*tk), n=lane&15
//   C[m][n]: n=lane&15, m=(lane>>4)*4+reg

namespace {

constexpr int kH = 512;
constexpr int kL = 2048;
constexpr int kChunks = 32;

typedef __attribute__((ext_vector_type(8))) short bf16x8;
typedef __attribute__((ext_vector_type(4))) float f32x4;

#define MFMA(A, B, C) __builtin_amdgcn_mfma_f32_16x16x32_bf16((A), (B), (C), 0, 0, 0)

__device__ inline unsigned int cvt_pk_bf16(float lo, float hi) {
  unsigned int r;
  asm("v_cvt_pk_bf16_f32 %0, %1, %2" : "=v"(r) : "v"(lo), "v"(hi));
  return r;
}

union B8U4 { bf16x8 v; unsigned int u[4]; };

__device__ inline void cvt_split8(const f32x4 a, const f32x4 b, bf16x8& fh, bf16x8& fl) {
  B8U4 H, L;
  float x[8];
  #pragma unroll
  for (int j = 0; j < 4; ++j) { x[j] = a[j]; x[4 + j] = b[j]; }
  #pragma unroll
  for (int d = 0; d < 4; ++d) {
    const float x0 = x[2 * d], x1 = x[2 * d + 1];
    const unsigned int hp = cvt_pk_bf16(x0, x1);
    const float h0 = __uint_as_float(hp << 16);
    const float h1 = __uint_as_float(hp & 0xFFFF0000u);
    H.u[d] = hp;
    L.u[d] = cvt_pk_bf16(x0 - h0, x1 - h1);
  }
  fh = H.v; fl = L.v;
}

// Toeplitz A-operand fragment from a 128-tap array: value = tp[n0 - j]
__device__ inline void gen_frag(const float* tp, int n0, bf16x8& fh, bf16x8& fl) {
  float t[8];
  #pragma unroll
  for (int j = 0; j < 8; ++j) {
    const int n = n0 - j;
    t[j] = (n >= 0 && n < 127) ? tp[n] : 0.0f;
  }
  const f32x4 a = {t[0], t[1], t[2], t[3]};
  const f32x4 b = {t[4], t[5], t[6], t[7]};
  cvt_split8(a, b, fh, fl);
}

// Toeplitz B-operand fragment: value = tp[base + j]  (base in [0,119])
__device__ inline void gen_fragB(const float* tp, int base, bf16x8& fh, bf16x8& fl) {
  float t[8];
  #pragma unroll
  for (int j = 0; j < 8; ++j) t[j] = tp[base + j];
  const f32x4 a = {t[0], t[1], t[2], t[3]};
  const f32x4 b = {t[4], t[5], t[6], t[7]};
  cvt_split8(a, b, fh, fl);
}

// LDS pool (69632 B -> 2 blocks/CU). Prologue stages alias the main-loop rings:
//   [     0, 17408) Astage f32[64][68]   | main: cring f32[2][16][68] (8704)
//                                        |       scratch f32[16][68] @8704 (4352)
//   [ 17408, 34816) Pstage f32[64][68]   | main: pring bf16x8[2][4][64] (8192)
//   [ 34816, 51200) G2S_T bf16x8[4][2][2][64]
//   [ 51200, 67584) Gp_T  bf16x8[4][2][2][64]
//   [ 67584, 69120) taps  f32[3][128]
//   [ 69120, 69632) wPad  f32[128]

__global__ __launch_bounds__(320, 3)
void ssm_mfma_kernel(const float* __restrict__ u,
                     const float* __restrict__ kin,
                     float* __restrict__ y) {
  const int h    = blockIdx.x;
  const int tid  = threadIdx.x;
  const int wid  = tid >> 6;
  const int lane = tid & 63;
  const int ln16 = lane & 15;    // batch col (B/C) / row m (A)
  const int quad = lane >> 4;

  __shared__ alignas(16) char pool[69632];
  auto Astage  = (float (*)[68]) (pool);
  auto Pstage  = (float (*)[68]) (pool + 17408);
  auto cring   = (float (*)[16][68]) (pool);           // [2][16][68]
  auto scratch = (float (*)[68]) (pool + 8704);        // [16][68]
  auto pring   = (bf16x8 (*)[4][64]) (pool + 17408);   // [2][4][64]
  auto G2S_T   = (bf16x8 (*)[2][2][64]) (pool + 34816);
  auto Gp_T    = (bf16x8 (*)[2][2][64]) (pool + 51200);
  auto taps    = (float (*)[128]) (pool + 67584);
  float* wPad  = (float*) (pool + 69120);

  // ---------------- taps: wave0 shuffle scans (proven) ---------------------
  if (wid == 0) {
    const float kv = kin[h * 64 + lane];
    const float kc = fminf(fmaxf(kv, 0.0625f), 1.0f);
    float ks = kc;
    #pragma unroll
    for (int off = 32; off >= 1; off >>= 1) ks += __shfl_xor(ks, off);
    const float kn = kc / ks;
    const float cc = 1.0f / (1.0f + kn);
    float pp = cc;
    #pragma unroll
    for (int off = 1; off < 64; off <<= 1) {
      const float t = __shfl_up(pp, off);
      if (lane >= off) pp *= t;
    }
    float Pe = __shfl_up(pp, 1);
    if (lane == 0) Pe = 1.0f;
    const float wv = (lane < 63) ? (kn * cc * Pe) : Pe;
    const float gv = kv * Pe;
    float sv = (lane == 0) ? 1.0f : 0.0f;
    for (int rr = 0; rr < 63; ++rr) {
      const float s0 = __shfl(sv, rr);
      const float cf = __shfl(wv, lane - 1 - rr);
      if (lane > rr) sv = fmaf(cf, s0, sv);
    }
    taps[0][lane] = 0.0f;
    taps[1][lane] = 0.0f;
    const float gn = __shfl(gv, lane + 1);
    taps[2][lane] = (lane < 63) ? gn : 0.0f;  // G1: g[(i-j)+64]
    taps[2][64 + lane] = 0.0f;
    taps[0][63 + lane] = sv;                  // S: s[i-j]
    taps[1][63 + lane] = gv;                  // G2: g[i-j]
    if (lane == 0) { taps[0][127] = 0.0f; taps[1][127] = 0.0f; }
    wPad[lane] = wv;
    wPad[64 + lane] = 0.0f;
  }
  __syncthreads();

  // ---------------- stage 1: A = S·W (4-term) -> Astage; G2S -> Pstage -----
  if (wid < 4) {
    const int mt = wid;
    bf16x8 xh[2], xl[2], g2h[2], g2l[2];
    #pragma unroll
    for (int tk = 0; tk < 2; ++tk) {
      const int n0 = 16 * mt + ln16 - (32 * tk + 8 * quad) + 63;
      gen_frag(taps[0], n0, xh[tk], xl[tk]);
      gen_frag(taps[1], n0, g2h[tk], g2l[tk]);
    }
    #pragma unroll
    for (int nt = 0; nt < 4; ++nt) {
      f32x4 accA = {0.f, 0.f, 0.f, 0.f};
      f32x4 accG = {0.f, 0.f, 0.f, 0.f};
      #pragma unroll
      for (int tk = 0; tk < 2; ++tk) {
        const int base = 8 * quad + 32 * tk - (16 * nt + ln16) + 63;
        bf16x8 bh, bl;
        gen_fragB(wPad, base, bh, bl);            // W as B: w[(k-n)+63]
        accA = MFMA(xh[tk], bh, accA);
        accA = MFMA(xh[tk], bl, accA);
        accA = MFMA(xl[tk], bh, accA);
        accA = MFMA(xl[tk], bl, accA);            // LL: A err ~2^-16
        bf16x8 sbh, sbl;
        gen_fragB(taps[0], base, sbh, sbl);       // S as B: s[k-n]
        accG = MFMA(g2h[tk], sbh, accG);
        accG = MFMA(g2h[tk], sbl, accG);
        accG = MFMA(g2l[tk], sbh, accG);
      }
      #pragma unroll
      for (int r = 0; r < 4; ++r) {
        Astage[16 * mt + 4 * quad + r][16 * nt + ln16] = accA[r];
        Pstage[16 * mt + 4 * quad + r][16 * nt + ln16] = accG[r];
      }
    }
  }
  __syncthreads();

  // ---------------- consumer S frags (regs) + G2S_T copy -------------------
  const int cmt = (wid >= 1) ? (wid - 1) : 0;   // consumer's mt tile
  bf16x8 sH[2], sL[2];
  if (wid >= 1) {
    #pragma unroll
    for (int tk = 0; tk < 2; ++tk) {
      const int n0 = 16 * cmt + ln16 - (32 * tk + 8 * quad) + 63;
      gen_frag(taps[0], n0, sH[tk], sL[tk]);
    }
  }
  if (wid < 4) {
    #pragma unroll
    for (int tk = 0; tk < 2; ++tk) {
      const int row = 16 * wid + ln16, k0 = 32 * tk + 8 * quad;
      const f32x4 a = *(const f32x4*)&Pstage[row][k0];
      const f32x4 b = *(const f32x4*)&Pstage[row][k0 + 4];
      bf16x8 fh, fl;
      cvt_split8(a, b, fh, fl);
      G2S_T[wid][tk][0][lane] = fh;
      G2S_T[wid][tk][1][lane] = fl;
    }
  }
  __syncthreads();

  // ---------------- G' = G1 + G2·A -> Pstage -------------------------------
  if (wid < 4) {
    const int mt = wid;
    bf16x8 g2h[2], g2l[2];
    #pragma unroll
    for (int tk = 0; tk < 2; ++tk) {
      const int n0 = 16 * mt + ln16 - (32 * tk + 8 * quad) + 63;
      gen_frag(taps[1], n0, g2h[tk], g2l[tk]);
    }
    #pragma unroll
    for (int nt = 0; nt < 4; ++nt) {
      f32x4 acc = {0.f, 0.f, 0.f, 0.f};
      #pragma unroll
      for (int tk = 0; tk < 2; ++tk) {
        float t[8];
        #pragma unroll
        for (int j = 0; j < 8; ++j)
          t[j] = Astage[8 * quad + 32 * tk + j][16 * nt + ln16];  // A as B
        const f32x4 a = {t[0], t[1], t[2], t[3]};
        const f32x4 b = {t[4], t[5], t[6], t[7]};
        bf16x8 bh, bl;
        cvt_split8(a, b, bh, bl);
        acc = MFMA(g2h[tk], bh, acc);
        acc = MFMA(g2h[tk], bl, acc);
        acc = MFMA(g2l[tk], bh, acc);
      }
      #pragma unroll
      for (int r = 0; r < 4; ++r) {
        const int i = 16 * mt + 4 * quad + r, j = 16 * nt + ln16;
        Pstage[i][j] = acc[r] + taps[2][(i - j) + 63];            // + G1
      }
    }
  }
  __syncthreads();

  // ---------------- Gp_T copy; wave0 A-frags -------------------------------
  bf16x8 aH[4][2], aL[4][2];
  if (wid < 4) {
    #pragma unroll
    for (int tk = 0; tk < 2; ++tk) {
      const int row = 16 * wid + ln16, k0 = 32 * tk + 8 * quad;
      const f32x4 a = *(const f32x4*)&Pstage[row][k0];
      const f32x4 b = *(const f32x4*)&Pstage[row][k0 + 4];
      bf16x8 fh, fl;
      cvt_split8(a, b, fh, fl);
      Gp_T[wid][tk][0][lane] = fh;
      Gp_T[wid][tk][1][lane] = fl;
    }
  }
  if (wid == 0) {
    #pragma unroll
    for (int mt = 0; mt < 4; ++mt) {
      #pragma unroll
      for (int tk = 0; tk < 2; ++tk) {
        const int row = 16 * mt + ln16, k0 = 32 * tk + 8 * quad;
        const f32x4 a = *(const f32x4*)&Astage[row][k0];
        const f32x4 b = *(const f32x4*)&Astage[row][k0 + 4];
        cvt_split8(a, b, aH[mt][tk], aL[mt][tk]);
      }
    }
  }
  __syncthreads();   // stages dead; rings (aliased) live from here

  // ---------------- main pipelined loop ------------------------------------
  bf16x8 pH[2], pL[2];
  {
    bf16x8 z;
    #pragma unroll
    for (int j = 0; j < 8; ++j) z[j] = 0;
    pH[0] = z; pH[1] = z; pL[0] = z; pL[1] = z;
  }

  const float* ub = u + ((size_t)ln16 * kH + h) * kL + 8 * quad;
  float* yb = y + ((size_t)ln16 * kH + h) * kL;

  f32x4 uv[4];
  if (wid >= 1) {
    #pragma unroll
    for (int i = 0; i < 4; ++i)
      uv[i] = *(const f32x4*)(ub + 32 * (i >> 1) + 4 * (i & 1));
  }
  f32x4 yuA = {0.f, 0.f, 0.f, 0.f}, yuB = {0.f, 0.f, 0.f, 0.f};

  auto step = [&](int s, f32x4& yu) {
    if (wid == 0) {
      // ------- producer: chunk m = s-1 -------
      if (s >= 1 && s <= kChunks) {
        const int par = (s - 1) & 1;
        pring[par][0][lane] = pH[0];     // publish PRE-state p_{s-1}
        pring[par][1][lane] = pH[1];
        pring[par][2][lane] = pL[0];
        pring[par][3][lane] = pL[1];
        f32x4 acc[4];
        #pragma unroll
        for (int mt = 0; mt < 4; ++mt)
          acc[mt] = *(const f32x4*)&cring[par][ln16][16 * mt + 4 * quad];
        #pragma unroll
        for (int mt = 0; mt < 4; ++mt) {
          #pragma unroll
          for (int tk = 0; tk < 2; ++tk) {
            acc[mt] = MFMA(aH[mt][tk], pH[tk], acc[mt]);
            acc[mt] = MFMA(aH[mt][tk], pL[tk], acc[mt]);
            acc[mt] = MFMA(aL[mt][tk], pH[tk], acc[mt]);
          }
          *(f32x4*)&scratch[ln16][16 * mt + 4 * quad] = acc[mt];
        }
        asm volatile("s_waitcnt lgkmcnt(0)" ::: "memory");
        __builtin_amdgcn_sched_barrier(0);
        #pragma unroll
        for (int tk = 0; tk < 2; ++tk) {
          const int k0 = 8 * quad + 32 * tk;
          const f32x4 ra = *(const f32x4*)&scratch[ln16][k0];
          const f32x4 rb = *(const f32x4*)&scratch[ln16][k0 + 4];
          cvt_split8(ra, rb, pH[tk], pL[tk]);   // new state p_s
        }
      }
    } else {
      // ------- consumer: own mt tile -------
      f32x4 accU = {0.f, 0.f, 0.f, 0.f};
      if (s < kChunks) {
        bf16x8 uH[2], uL[2];
        cvt_split8(uv[0], uv[1], uH[0], uL[0]);
        cvt_split8(uv[2], uv[3], uH[1], uL[1]);
        const int tn = (s + 1 < kChunks) ? 64 * (s + 1) : 0;  // prefetch
        #pragma unroll
        for (int i = 0; i < 4; ++i)
          uv[i] = *(const f32x4*)(ub + tn + 32 * (i >> 1) + 4 * (i & 1));
        // c_s[cmt] = S·u
        f32x4 accC = {0.f, 0.f, 0.f, 0.f};
        #pragma unroll
        for (int tk = 0; tk < 2; ++tk) {
          accC = MFMA(sH[tk], uH[tk], accC);
          accC = MFMA(sH[tk], uL[tk], accC);
          accC = MFMA(sL[tk], uH[tk], accC);
        }
        *(f32x4*)&cring[s & 1][ln16][16 * cmt + 4 * quad] = accC;
        // yu_s[cmt] = G2S·u
        #pragma unroll
        for (int tk = 0; tk < 2; ++tk) {
          const bf16x8 gh = G2S_T[cmt][tk][0][lane];
          const bf16x8 gl = G2S_T[cmt][tk][1][lane];
          accU = MFMA(gh, uH[tk], accU);
          accU = MFMA(gh, uL[tk], accU);
          accU = MFMA(gl, uH[tk], accU);
        }
      }
      if (s >= 2) {
        // finish y_{s-2}[cmt] = yu_{s-2} + G'·p_{s-2}
        bf16x8 pfH[2], pfL[2];
        pfH[0] = pring[s & 1][0][lane];
        pfH[1] = pring[s & 1][1][lane];
        pfL[0] = pring[s & 1][2][lane];
        pfL[1] = pring[s & 1][3][lane];
        f32x4 accY = yu;                 // read BEFORE overwrite below
        #pragma unroll
        for (int tk = 0; tk < 2; ++tk) {
          const bf16x8 gh = Gp_T[cmt][tk][0][lane];
          const bf16x8 gl = Gp_T[cmt][tk][1][lane];
          accY = MFMA(gh, pfH[tk], accY);
          accY = MFMA(gh, pfL[tk], accY);
          accY = MFMA(gl, pfH[tk], accY);
        }
        *(f32x4*)(yb + 64 * (s - 2) + 16 * cmt + 4 * quad) = accY;
      }
      yu = accU;
    }
    // step barrier: drain LDS only; u loads / y stores stay in flight
    asm volatile("s_waitcnt lgkmcnt(0)" ::: "memory");
    __builtin_amdgcn_s_barrier();
    asm volatile("" ::: "memory");
  };

  // 34 steps; yu parity via 2x unroll (rule #20: no runtime reg-array index)
  #pragma unroll 1
  for (int i = 0; i < 17; ++i) {
    step(2 * i,     yuA);
    step(2 * i + 1, yuB);
  }
}

}  // namespace

extern "C" void kernel_launch(void* const* d_in, const int* in_sizes, int n_in,
                              void* d_out, int out_size, void* d_ws, size_t ws_size,
                              hipStream_t stream) {
  const float* u  = (const float*)d_in[0];   // (16, 512, 2048) fp32
  const float* kk = (const float*)d_in[1];   // (1, 512, 64)    fp32
  if (n_in >= 2 && in_sizes[0] < in_sizes[1]) {
    const float* t = u; u = kk; kk = t;
  }
  float* yy = (float*)d_out;                 // (16, 512, 2048) fp32
  hipLaunchKernelGGL(ssm_mfma_kernel, dim3(kH), dim3(320), 0, stream, u, kk, yy);
}

// Round 5
// 150.061 us; speedup vs baseline: 1.2819x; 1.2819x over previous
//
#include <hip/hip_runtime.h>

// StateSpaceDiffusionModel — MFMA formulation, round 7: register-isomorphic
// 2-wave producer/consumer.
//
//   c_m  = S·u_m                    (wave1)
//   p_{m+1} = A·p_m + c_m           (A = S·W dense; serial; wave0)
//   y_m  = G'·p_m + G2S·u_m         (G' = G1 + G2·A; split: G2S·u on wave1,
//                                    G'·p + finish on wave0 — p is in regs!)
//
// Round-4 post-mortem: wid-divergent designs allocate the UNION of both
// branches' loop-live registers; with a launch_bounds cap the operator
// fragments spilled to scratch (VGPR_Count=80) -> 8000cy/step. Fix: both
// waves use the SAME register variables (oxH/oxL, oyH/oyL, opH/opL) with
// different contents:
//   wave0: ox=A, oy=G', op=p (state frags, renewed via scratch round-trip);
//          accX -> scratch (r -> new p), accY -> global y.
//   wave1: ox=S, oy=G2S, op=u (frags from prefetched uv);
//          accX -> cring[par], accY -> yuring[par].
// The per-step MFMA block is literally identical for both waves (48 MFMA);
// no pring (wave0 computes y from its own p). 2 waves/block, 512 blocks ->
// 2 blocks/CU, 1 wave/SIMD, launch_bounds(128,1) => no VGPR cap, no spill.
// LDS 36.9KB: prologue stages alias main-loop rings. One lgkm-only barrier
// per step (u loads / y stores stay in flight), 33 steps.
// Numerics identical to rounds 3/4 (A 4-term, G'/G2S 3-term, data 3-term
// hi/lo bf16) -> same absmax.
//
// mfma_f32_16x16x32_bf16 layouts (m89/m120):
//   A[m][k]: m=lane&15, k=(lane>>4)*8+j (+32*tk)
//   B[k][n]: k=(lane>>4)*8+j (+32*tk), n=lane&15
//   C[m][n]: n=lane&15, m=(lane>>4)*4+reg

namespace {

constexpr int kH = 512;
constexpr int kL = 2048;
constexpr int kChunks = 32;

typedef __attribute__((ext_vector_type(8))) short bf16x8;
typedef __attribute__((ext_vector_type(4))) float f32x4;

#define MFMA(A, B, C) __builtin_amdgcn_mfma_f32_16x16x32_bf16((A), (B), (C), 0, 0, 0)

__device__ inline unsigned int cvt_pk_bf16(float lo, float hi) {
  unsigned int r;
  asm("v_cvt_pk_bf16_f32 %0, %1, %2" : "=v"(r) : "v"(lo), "v"(hi));
  return r;
}

union B8U4 { bf16x8 v; unsigned int u[4]; };

__device__ inline void cvt_split8(const f32x4 a, const f32x4 b, bf16x8& fh, bf16x8& fl) {
  B8U4 H, L;
  float x[8];
  #pragma unroll
  for (int j = 0; j < 4; ++j) { x[j] = a[j]; x[4 + j] = b[j]; }
  #pragma unroll
  for (int d = 0; d < 4; ++d) {
    const float x0 = x[2 * d], x1 = x[2 * d + 1];
    const unsigned int hp = cvt_pk_bf16(x0, x1);
    const float h0 = __uint_as_float(hp << 16);
    const float h1 = __uint_as_float(hp & 0xFFFF0000u);
    H.u[d] = hp;
    L.u[d] = cvt_pk_bf16(x0 - h0, x1 - h1);
  }
  fh = H.v; fl = L.v;
}

// Toeplitz A-operand fragment from a 128-tap array: value = tp[n0 - j]
__device__ inline void gen_frag(const float* tp, int n0, bf16x8& fh, bf16x8& fl) {
  float t[8];
  #pragma unroll
  for (int j = 0; j < 8; ++j) {
    const int n = n0 - j;
    t[j] = (n >= 0 && n < 127) ? tp[n] : 0.0f;
  }
  const f32x4 a = {t[0], t[1], t[2], t[3]};
  const f32x4 b = {t[4], t[5], t[6], t[7]};
  cvt_split8(a, b, fh, fl);
}

// Toeplitz B-operand fragment: value = tp[base + j]  (base in [0,119])
__device__ inline void gen_fragB(const float* tp, int base, bf16x8& fh, bf16x8& fl) {
  float t[8];
  #pragma unroll
  for (int j = 0; j < 8; ++j) t[j] = tp[base + j];
  const f32x4 a = {t[0], t[1], t[2], t[3]};
  const f32x4 b = {t[4], t[5], t[6], t[7]};
  cvt_split8(a, b, fh, fl);
}

// LDS pool, 36864 B. Prologue stages alias main-loop buffers:
//   [     0, 17408) Astage f32[64][68]  | main: cring  f32[2][16][68] (0..8704)
//                                       |       yuring f32[2][16][68] (8704..17408)
//   [ 17408, 34816) Pstage f32[64][68]  | main: scratch f32[16][68] (17408..21760)
//   [ 34816, 36352) taps f32[3][128]
//   [ 36352, 36864) wPad f32[128]

__global__ __launch_bounds__(128, 1)
void ssm_mfma_kernel(const float* __restrict__ u,
                     const float* __restrict__ kin,
                     float* __restrict__ y) {
  const int h    = blockIdx.x;
  const int tid  = threadIdx.x;
  const int wid  = tid >> 6;
  const int lane = tid & 63;
  const int ln16 = lane & 15;    // batch col (B/C) / row m (A)
  const int quad = lane >> 4;

  __shared__ alignas(16) char pool[36864];
  auto Astage  = (float (*)[68]) (pool);
  auto Pstage  = (float (*)[68]) (pool + 17408);
  auto cring   = (float (*)[16][68]) (pool);           // [2][16][68]
  auto yuring  = (float (*)[16][68]) (pool + 8704);    // [2][16][68]
  auto scratch = (float (*)[68]) (pool + 17408);       // [16][68]
  auto taps    = (float (*)[128]) (pool + 34816);
  float* wPad  = (float*) (pool + 36352);

  // ---------------- taps: wave0 shuffle scans (proven) ---------------------
  if (wid == 0) {
    const float kv = kin[h * 64 + lane];
    const float kc = fminf(fmaxf(kv, 0.0625f), 1.0f);
    float ks = kc;
    #pragma unroll
    for (int off = 32; off >= 1; off >>= 1) ks += __shfl_xor(ks, off);
    const float kn = kc / ks;
    const float cc = 1.0f / (1.0f + kn);
    float pp = cc;
    #pragma unroll
    for (int off = 1; off < 64; off <<= 1) {
      const float t = __shfl_up(pp, off);
      if (lane >= off) pp *= t;
    }
    float Pe = __shfl_up(pp, 1);
    if (lane == 0) Pe = 1.0f;
    const float wv = (lane < 63) ? (kn * cc * Pe) : Pe;
    const float gv = kv * Pe;
    float sv = (lane == 0) ? 1.0f : 0.0f;
    for (int rr = 0; rr < 63; ++rr) {
      const float s0 = __shfl(sv, rr);
      const float cf = __shfl(wv, lane - 1 - rr);
      if (lane > rr) sv = fmaf(cf, s0, sv);
    }
    taps[0][lane] = 0.0f;
    taps[1][lane] = 0.0f;
    const float gn = __shfl(gv, lane + 1);
    taps[2][lane] = (lane < 63) ? gn : 0.0f;  // G1: g[(i-j)+64]
    taps[2][64 + lane] = 0.0f;
    taps[0][63 + lane] = sv;                  // S: s[i-j]
    taps[1][63 + lane] = gv;                  // G2: g[i-j]
    if (lane == 0) { taps[0][127] = 0.0f; taps[1][127] = 0.0f; }
    wPad[lane] = wv;
    wPad[64 + lane] = 0.0f;
  }
  __syncthreads();

  // ------- stage 2: A = S·W (4-term) -> Astage; G2S = G2·S -> Pstage -------
  // 2 mt tiles per wave.
  #pragma unroll
  for (int t2 = 0; t2 < 2; ++t2) {
    const int mt = 2 * wid + t2;
    bf16x8 xh[2], xl[2], g2h[2], g2l[2];
    #pragma unroll
    for (int tk = 0; tk < 2; ++tk) {
      const int n0 = 16 * mt + ln16 - (32 * tk + 8 * quad) + 63;
      gen_frag(taps[0], n0, xh[tk], xl[tk]);
      gen_frag(taps[1], n0, g2h[tk], g2l[tk]);
    }
    #pragma unroll
    for (int nt = 0; nt < 4; ++nt) {
      f32x4 accA = {0.f, 0.f, 0.f, 0.f};
      f32x4 accG = {0.f, 0.f, 0.f, 0.f};
      #pragma unroll
      for (int tk = 0; tk < 2; ++tk) {
        const int base = 8 * quad + 32 * tk - (16 * nt + ln16) + 63;
        bf16x8 bh, bl;
        gen_fragB(wPad, base, bh, bl);            // W as B: w[(k-n)+63]
        accA = MFMA(xh[tk], bh, accA);
        accA = MFMA(xh[tk], bl, accA);
        accA = MFMA(xl[tk], bh, accA);
        accA = MFMA(xl[tk], bl, accA);            // LL: A err ~2^-16
        bf16x8 sbh, sbl;
        gen_fragB(taps[0], base, sbh, sbl);       // S as B: s[k-n]
        accG = MFMA(g2h[tk], sbh, accG);
        accG = MFMA(g2h[tk], sbl, accG);
        accG = MFMA(g2l[tk], sbh, accG);
      }
      #pragma unroll
      for (int r = 0; r < 4; ++r) {
        Astage[16 * mt + 4 * quad + r][16 * nt + ln16] = accA[r];
        Pstage[16 * mt + 4 * quad + r][16 * nt + ln16] = accG[r];
      }
    }
  }
  __syncthreads();

  // ------- stage 3: wave1 operator frags: ox=S (taps), oy=G2S (Pstage) -----
  bf16x8 oxH[4][2], oxL[4][2], oyH[4][2], oyL[4][2];
  if (wid == 1) {
    #pragma unroll
    for (int mt = 0; mt < 4; ++mt) {
      #pragma unroll
      for (int tk = 0; tk < 2; ++tk) {
        const int n0 = 16 * mt + ln16 - (32 * tk + 8 * quad) + 63;
        gen_frag(taps[0], n0, oxH[mt][tk], oxL[mt][tk]);      // S
        const int row = 16 * mt + ln16, k0 = 32 * tk + 8 * quad;
        const f32x4 a = *(const f32x4*)&Pstage[row][k0];
        const f32x4 b = *(const f32x4*)&Pstage[row][k0 + 4];
        cvt_split8(a, b, oyH[mt][tk], oyL[mt][tk]);           // G2S
      }
    }
  }
  __syncthreads();

  // ------- stage 4: G' = G1 + G2·A -> Pstage (2 mt tiles per wave) ---------
  #pragma unroll
  for (int t2 = 0; t2 < 2; ++t2) {
    const int mt = 2 * wid + t2;
    bf16x8 g2h[2], g2l[2];
    #pragma unroll
    for (int tk = 0; tk < 2; ++tk) {
      const int n0 = 16 * mt + ln16 - (32 * tk + 8 * quad) + 63;
      gen_frag(taps[1], n0, g2h[tk], g2l[tk]);
    }
    #pragma unroll
    for (int nt = 0; nt < 4; ++nt) {
      f32x4 acc = {0.f, 0.f, 0.f, 0.f};
      #pragma unroll
      for (int tk = 0; tk < 2; ++tk) {
        float t[8];
        #pragma unroll
        for (int j = 0; j < 8; ++j)
          t[j] = Astage[8 * quad + 32 * tk + j][16 * nt + ln16];  // A as B
        const f32x4 a = {t[0], t[1], t[2], t[3]};
        const f32x4 b = {t[4], t[5], t[6], t[7]};
        bf16x8 bh, bl;
        cvt_split8(a, b, bh, bl);
        acc = MFMA(g2h[tk], bh, acc);
        acc = MFMA(g2h[tk], bl, acc);
        acc = MFMA(g2l[tk], bh, acc);
      }
      #pragma unroll
      for (int r = 0; r < 4; ++r) {
        const int i = 16 * mt + 4 * quad + r, j = 16 * nt + ln16;
        Pstage[i][j] = acc[r] + taps[2][(i - j) + 63];            // + G1
      }
    }
  }
  __syncthreads();

  // ------- stage 5: wave0 operator frags: ox=A (Astage), oy=G' (Pstage) ----
  if (wid == 0) {
    #pragma unroll
    for (int mt = 0; mt < 4; ++mt) {
      #pragma unroll
      for (int tk = 0; tk < 2; ++tk) {
        const int row = 16 * mt + ln16, k0 = 32 * tk + 8 * quad;
        f32x4 a = *(const f32x4*)&Astage[row][k0];
        f32x4 b = *(const f32x4*)&Astage[row][k0 + 4];
        cvt_split8(a, b, oxH[mt][tk], oxL[mt][tk]);           // A
        a = *(const f32x4*)&Pstage[row][k0];
        b = *(const f32x4*)&Pstage[row][k0 + 4];
        cvt_split8(a, b, oyH[mt][tk], oyL[mt][tk]);           // G'
      }
    }
  }
  __syncthreads();   // stages dead; rings/scratch (aliased) live from here

  // ---------------- main pipelined loop ------------------------------------
  // opH/opL: wave0 = state-p frags (zero init); wave1 = u frags (from uv)
  bf16x8 opH[2], opL[2];
  {
    bf16x8 z;
    #pragma unroll
    for (int j = 0; j < 8; ++j) z[j] = 0;
    opH[0] = z; opH[1] = z; opL[0] = z; opL[1] = z;
  }

  const float* ub = u + ((size_t)ln16 * kH + h) * kL + 8 * quad;
  float* yb = y + ((size_t)ln16 * kH + h) * kL;

  f32x4 uv[4];
  if (wid == 1) {
    #pragma unroll
    for (int i = 0; i < 4; ++i)
      uv[i] = *(const f32x4*)(ub + 32 * (i >> 1) + 4 * (i & 1));
  }

  #pragma unroll 1
  for (int s = 0; s <= kChunks; ++s) {
    if (wid == 1) {
      // ------- u-side wave: produce c_s, yu_s -------
      if (s < kChunks) {
        cvt_split8(uv[0], uv[1], opH[0], opL[0]);
        cvt_split8(uv[2], uv[3], opH[1], opL[1]);
        const int tn = (s + 1 < kChunks) ? 64 * (s + 1) : 0;  // prefetch
        #pragma unroll
        for (int i = 0; i < 4; ++i)
          uv[i] = *(const f32x4*)(ub + tn + 32 * (i >> 1) + 4 * (i & 1));
        const int par = s & 1;
        #pragma unroll
        for (int mt = 0; mt < 4; ++mt) {
          f32x4 aX = {0.f, 0.f, 0.f, 0.f};
          f32x4 aY = {0.f, 0.f, 0.f, 0.f};
          #pragma unroll
          for (int tk = 0; tk < 2; ++tk) {
            aX = MFMA(oxH[mt][tk], opH[tk], aX);   // S·u
            aX = MFMA(oxH[mt][tk], opL[tk], aX);
            aX = MFMA(oxL[mt][tk], opH[tk], aX);
            aY = MFMA(oyH[mt][tk], opH[tk], aY);   // G2S·u
            aY = MFMA(oyH[mt][tk], opL[tk], aY);
            aY = MFMA(oyL[mt][tk], opH[tk], aY);
          }
          *(f32x4*)&cring[par][ln16][16 * mt + 4 * quad] = aX;
          *(f32x4*)&yuring[par][ln16][16 * mt + 4 * quad] = aY;
        }
      }
    } else {
      // ------- recurrence wave: consume c_{s-1}, yu_{s-1}; emit y_{s-1} ----
      if (s >= 1) {
        const int par = (s - 1) & 1;
        f32x4 aX[4], aY[4];
        #pragma unroll
        for (int mt = 0; mt < 4; ++mt) {
          aX[mt] = *(const f32x4*)&cring[par][ln16][16 * mt + 4 * quad];
          aY[mt] = *(const f32x4*)&yuring[par][ln16][16 * mt + 4 * quad];
        }
        #pragma unroll
        for (int mt = 0; mt < 4; ++mt) {
          #pragma unroll
          for (int tk = 0; tk < 2; ++tk) {
            aX[mt] = MFMA(oxH[mt][tk], opH[tk], aX[mt]);   // A·p + c
            aX[mt] = MFMA(oxH[mt][tk], opL[tk], aX[mt]);
            aX[mt] = MFMA(oxL[mt][tk], opH[tk], aX[mt]);
            aY[mt] = MFMA(oyH[mt][tk], opH[tk], aY[mt]);   // G'·p + yu
            aY[mt] = MFMA(oyH[mt][tk], opL[tk], aY[mt]);
            aY[mt] = MFMA(oyL[mt][tk], opH[tk], aY[mt]);
          }
        }
        #pragma unroll
        for (int mt = 0; mt < 4; ++mt) {
          *(f32x4*)&scratch[ln16][16 * mt + 4 * quad] = aX[mt];            // r
          *(f32x4*)(yb + 64 * (s - 1) + 16 * mt + 4 * quad) = aY[mt];      // y
        }
        // intra-wave round-trip: r (C layout) -> B-layout frags = new p
        asm volatile("s_waitcnt lgkmcnt(0)" ::: "memory");
        __builtin_amdgcn_sched_barrier(0);
        #pragma unroll
        for (int tk = 0; tk < 2; ++tk) {
          const int k0 = 8 * quad + 32 * tk;
          const f32x4 ra = *(const f32x4*)&scratch[ln16][k0];
          const f32x4 rb = *(const f32x4*)&scratch[ln16][k0 + 4];
          cvt_split8(ra, rb, opH[tk], opL[tk]);
        }
      }
    }
    // step barrier: drain LDS only; u loads / y stores stay in flight
    asm volatile("s_waitcnt lgkmcnt(0)" ::: "memory");
    __builtin_amdgcn_s_barrier();
    asm volatile("" ::: "memory");
  }
}

}  // namespace

extern "C" void kernel_launch(void* const* d_in, const int* in_sizes, int n_in,
                              void* d_out, int out_size, void* d_ws, size_t ws_size,
                              hipStream_t stream) {
  const float* u  = (const float*)d_in[0];   // (16, 512, 2048) fp32
  const float* kk = (const float*)d_in[1];   // (1, 512, 64)    fp32
  if (n_in >= 2 && in_sizes[0] < in_sizes[1]) {
    const float* t = u; u = kk; kk = t;
  }
  float* yy = (float*)d_out;                 // (16, 512, 2048) fp32
  hipLaunchKernelGGL(ssm_mfma_kernel, dim3(kH), dim3(128), 0, stream, u, kk, yy);
}

// Round 6
// 145.872 us; speedup vs baseline: 1.3188x; 1.0287x over previous
//
#include <hip/hip_runtime.h>

// StateSpaceDiffusionModel — MFMA formulation, round 8: one-operator-per-wave.
//
//   c_m  = S·u_m                    (wave2 -> cring)
//   yu_m = G2S·u_m                  (wave3 -> yuring)
//   r_m  = A·p_m + c_m              (wave0 -> sring; p_m = r_{m-1}, serial)
//   y_m  = G'·p_m + yu_m            (wave1 -> global)
// with A = S·W, G2S = G2·S, G' = G1 + G2·A precomputed per head by MFMA.
//
// Round-5 post-mortem: two operators per wave = 128 VGPR of frags + working
// set ≈ 200 loop-live VGPRs; allocator kept 104 -> ~100 VGPRs spilled to
// scratch, reloaded EVERY step (4730cy/step, same wall as round 2's 4755).
// Fix: ONE operator per wave (64 VGPR frags), 24 MFMA/step/wave, and all
// four wid-branches reuse the SAME register variables (oxH/oxL, opH/opL,
// uv, acc) so the divergent-branch union stays ~140 VGPR -> no spill.
// wave0's scratch round-trip is gone: it re-reads its own r from sring at
// the next step's start (same f32 values -> bit-identical numerics).
//
// Rings (LDS, alias prologue stages; f32 [16 batch][68 time]):
//   sring[3]: r_m written step m+1, read by wave0 @m+2 (as p), wave1 @m+3
//   cring[2]: c_m written step m (wave2), read step m+1 (wave0)
//   yuring[3]: yu_m written step m (wave3), read step m+2 (wave1)
// One lgkm-only barrier per step; u loads / y stores stay in flight.
// 8 waves/CU (2 blocks x 4 waves), 2 waves/SIMD -> per-SIMD MFMA demand
// 2x24x19.4 ≈ 930cy/step; cvt/ds overlap across waves.
//
// mfma_f32_16x16x32_bf16 layouts (m89/m120):
//   A[m][k]: m=lane&15, k=(lane>>4)*8+j (+32*tk)
//   B[k][n]: k=(lane>>4)*8+j (+32*tk), n=lane&15
//   C[m][n]: n=lane&15, m=(lane>>4)*4+reg

namespace {

constexpr int kH = 512;
constexpr int kL = 2048;
constexpr int kChunks = 32;

typedef __attribute__((ext_vector_type(8))) short bf16x8;
typedef __attribute__((ext_vector_type(4))) float f32x4;

#define MFMA(A, B, C) __builtin_amdgcn_mfma_f32_16x16x32_bf16((A), (B), (C), 0, 0, 0)

__device__ inline unsigned int cvt_pk_bf16(float lo, float hi) {
  unsigned int r;
  asm("v_cvt_pk_bf16_f32 %0, %1, %2" : "=v"(r) : "v"(lo), "v"(hi));
  return r;
}

union B8U4 { bf16x8 v; unsigned int u[4]; };

__device__ inline void cvt_split8(const f32x4 a, const f32x4 b, bf16x8& fh, bf16x8& fl) {
  B8U4 H, L;
  float x[8];
  #pragma unroll
  for (int j = 0; j < 4; ++j) { x[j] = a[j]; x[4 + j] = b[j]; }
  #pragma unroll
  for (int d = 0; d < 4; ++d) {
    const float x0 = x[2 * d], x1 = x[2 * d + 1];
    const unsigned int hp = cvt_pk_bf16(x0, x1);
    const float h0 = __uint_as_float(hp << 16);
    const float h1 = __uint_as_float(hp & 0xFFFF0000u);
    H.u[d] = hp;
    L.u[d] = cvt_pk_bf16(x0 - h0, x1 - h1);
  }
  fh = H.v; fl = L.v;
}

// Toeplitz A-operand fragment from a 128-tap array: value = tp[n0 - j]
__device__ inline void gen_frag(const float* tp, int n0, bf16x8& fh, bf16x8& fl) {
  float t[8];
  #pragma unroll
  for (int j = 0; j < 8; ++j) {
    const int n = n0 - j;
    t[j] = (n >= 0 && n < 127) ? tp[n] : 0.0f;
  }
  const f32x4 a = {t[0], t[1], t[2], t[3]};
  const f32x4 b = {t[4], t[5], t[6], t[7]};
  cvt_split8(a, b, fh, fl);
}

// Toeplitz B-operand fragment: value = tp[base + j]  (base in [0,119])
__device__ inline void gen_fragB(const float* tp, int base, bf16x8& fh, bf16x8& fl) {
  float t[8];
  #pragma unroll
  for (int j = 0; j < 8; ++j) t[j] = tp[base + j];
  const f32x4 a = {t[0], t[1], t[2], t[3]};
  const f32x4 b = {t[4], t[5], t[6], t[7]};
  cvt_split8(a, b, fh, fl);
}

// LDS pool, 36864 B. Prologue stages alias the main-loop rings:
//   [     0, 17408) Astage f32[64][68] | main: sring  f32[3][16][68] @0     (13056)
//                                      |       cring  f32[2][16][68] @13056 ( 8704)
//   [ 17408, 34816) Pstage f32[64][68] |       yuring f32[3][16][68] @21760 (13056)
//   [ 34816, 36352) taps f32[3][128]
//   [ 36352, 36864) wPad f32[128]

__global__ __launch_bounds__(256, 1)
void ssm_mfma_kernel(const float* __restrict__ u,
                     const float* __restrict__ kin,
                     float* __restrict__ y) {
  const int h    = blockIdx.x;
  const int tid  = threadIdx.x;
  const int wid  = tid >> 6;
  const int lane = tid & 63;
  const int ln16 = lane & 15;    // batch col (B/C) / row m (A)
  const int quad = lane >> 4;

  __shared__ alignas(16) char pool[36864];
  auto Astage  = (float (*)[68]) (pool);
  auto Pstage  = (float (*)[68]) (pool + 17408);
  auto sring   = (float (*)[16][68]) (pool);           // [3][16][68]
  auto cring   = (float (*)[16][68]) (pool + 13056);   // [2][16][68]
  auto yuring  = (float (*)[16][68]) (pool + 21760);   // [3][16][68]
  auto taps    = (float (*)[128]) (pool + 34816);
  float* wPad  = (float*) (pool + 36352);

  // ---------------- taps: wave0 shuffle scans (proven) ---------------------
  if (wid == 0) {
    const float kv = kin[h * 64 + lane];
    const float kc = fminf(fmaxf(kv, 0.0625f), 1.0f);
    float ks = kc;
    #pragma unroll
    for (int off = 32; off >= 1; off >>= 1) ks += __shfl_xor(ks, off);
    const float kn = kc / ks;
    const float cc = 1.0f / (1.0f + kn);
    float pp = cc;
    #pragma unroll
    for (int off = 1; off < 64; off <<= 1) {
      const float t = __shfl_up(pp, off);
      if (lane >= off) pp *= t;
    }
    float Pe = __shfl_up(pp, 1);
    if (lane == 0) Pe = 1.0f;
    const float wv = (lane < 63) ? (kn * cc * Pe) : Pe;
    const float gv = kv * Pe;
    float sv = (lane == 0) ? 1.0f : 0.0f;
    for (int rr = 0; rr < 63; ++rr) {
      const float s0 = __shfl(sv, rr);
      const float cf = __shfl(wv, lane - 1 - rr);
      if (lane > rr) sv = fmaf(cf, s0, sv);
    }
    taps[0][lane] = 0.0f;
    taps[1][lane] = 0.0f;
    const float gn = __shfl(gv, lane + 1);
    taps[2][lane] = (lane < 63) ? gn : 0.0f;  // G1: g[(i-j)+64]
    taps[2][64 + lane] = 0.0f;
    taps[0][63 + lane] = sv;                  // S: s[i-j]
    taps[1][63 + lane] = gv;                  // G2: g[i-j]
    if (lane == 0) { taps[0][127] = 0.0f; taps[1][127] = 0.0f; }
    wPad[lane] = wv;
    wPad[64 + lane] = 0.0f;
  }
  __syncthreads();

  // ------- stage 2: A = S·W (4-term) -> Astage; G2S = G2·S -> Pstage -------
  // one mt tile per wave
  {
    const int mt = wid;
    bf16x8 xh[2], xl[2], g2h[2], g2l[2];
    #pragma unroll
    for (int tk = 0; tk < 2; ++tk) {
      const int n0 = 16 * mt + ln16 - (32 * tk + 8 * quad) + 63;
      gen_frag(taps[0], n0, xh[tk], xl[tk]);
      gen_frag(taps[1], n0, g2h[tk], g2l[tk]);
    }
    #pragma unroll
    for (int nt = 0; nt < 4; ++nt) {
      f32x4 accA = {0.f, 0.f, 0.f, 0.f};
      f32x4 accG = {0.f, 0.f, 0.f, 0.f};
      #pragma unroll
      for (int tk = 0; tk < 2; ++tk) {
        const int base = 8 * quad + 32 * tk - (16 * nt + ln16) + 63;
        bf16x8 bh, bl;
        gen_fragB(wPad, base, bh, bl);            // W as B: w[(k-n)+63]
        accA = MFMA(xh[tk], bh, accA);
        accA = MFMA(xh[tk], bl, accA);
        accA = MFMA(xl[tk], bh, accA);
        accA = MFMA(xl[tk], bl, accA);            // LL: A err ~2^-16
        bf16x8 sbh, sbl;
        gen_fragB(taps[0], base, sbh, sbl);       // S as B: s[k-n]
        accG = MFMA(g2h[tk], sbh, accG);
        accG = MFMA(g2h[tk], sbl, accG);
        accG = MFMA(g2l[tk], sbh, accG);
      }
      #pragma unroll
      for (int r = 0; r < 4; ++r) {
        Astage[16 * mt + 4 * quad + r][16 * nt + ln16] = accA[r];
        Pstage[16 * mt + 4 * quad + r][16 * nt + ln16] = accG[r];
      }
    }
  }
  __syncthreads();

  // ------- stage 3: wave2 ox=S (taps); wave3 ox=G2S (Pstage, pre-overwrite)
  bf16x8 oxH[4][2], oxL[4][2];
  if (wid == 2) {
    #pragma unroll
    for (int mt = 0; mt < 4; ++mt) {
      #pragma unroll
      for (int tk = 0; tk < 2; ++tk) {
        const int n0 = 16 * mt + ln16 - (32 * tk + 8 * quad) + 63;
        gen_frag(taps[0], n0, oxH[mt][tk], oxL[mt][tk]);      // S
      }
    }
  } else if (wid == 3) {
    #pragma unroll
    for (int mt = 0; mt < 4; ++mt) {
      #pragma unroll
      for (int tk = 0; tk < 2; ++tk) {
        const int row = 16 * mt + ln16, k0 = 32 * tk + 8 * quad;
        const f32x4 a = *(const f32x4*)&Pstage[row][k0];
        const f32x4 b = *(const f32x4*)&Pstage[row][k0 + 4];
        cvt_split8(a, b, oxH[mt][tk], oxL[mt][tk]);           // G2S
      }
    }
  }
  __syncthreads();

  // ------- stage 4: G' = G1 + G2·A -> Pstage (one mt tile per wave) --------
  {
    const int mt = wid;
    bf16x8 g2h[2], g2l[2];
    #pragma unroll
    for (int tk = 0; tk < 2; ++tk) {
      const int n0 = 16 * mt + ln16 - (32 * tk + 8 * quad) + 63;
      gen_frag(taps[1], n0, g2h[tk], g2l[tk]);
    }
    #pragma unroll
    for (int nt = 0; nt < 4; ++nt) {
      f32x4 acc = {0.f, 0.f, 0.f, 0.f};
      #pragma unroll
      for (int tk = 0; tk < 2; ++tk) {
        float t[8];
        #pragma unroll
        for (int j = 0; j < 8; ++j)
          t[j] = Astage[8 * quad + 32 * tk + j][16 * nt + ln16];  // A as B
        const f32x4 a = {t[0], t[1], t[2], t[3]};
        const f32x4 b = {t[4], t[5], t[6], t[7]};
        bf16x8 bh, bl;
        cvt_split8(a, b, bh, bl);
        acc = MFMA(g2h[tk], bh, acc);
        acc = MFMA(g2h[tk], bl, acc);
        acc = MFMA(g2l[tk], bh, acc);
      }
      #pragma unroll
      for (int r = 0; r < 4; ++r) {
        const int i = 16 * mt + 4 * quad + r, j = 16 * nt + ln16;
        Pstage[i][j] = acc[r] + taps[2][(i - j) + 63];            // + G1
      }
    }
  }
  __syncthreads();

  // ------- stage 5: wave0 ox=A (Astage); wave1 ox=G' (Pstage) --------------
  if (wid == 0) {
    #pragma unroll
    for (int mt = 0; mt < 4; ++mt) {
      #pragma unroll
      for (int tk = 0; tk < 2; ++tk) {
        const int row = 16 * mt + ln16, k0 = 32 * tk + 8 * quad;
        const f32x4 a = *(const f32x4*)&Astage[row][k0];
        const f32x4 b = *(const f32x4*)&Astage[row][k0 + 4];
        cvt_split8(a, b, oxH[mt][tk], oxL[mt][tk]);           // A
      }
    }
  } else if (wid == 1) {
    #pragma unroll
    for (int mt = 0; mt < 4; ++mt) {
      #pragma unroll
      for (int tk = 0; tk < 2; ++tk) {
        const int row = 16 * mt + ln16, k0 = 32 * tk + 8 * quad;
        const f32x4 a = *(const f32x4*)&Pstage[row][k0];
        const f32x4 b = *(const f32x4*)&Pstage[row][k0 + 4];
        cvt_split8(a, b, oxH[mt][tk], oxL[mt][tk]);           // G'
      }
    }
  }
  __syncthreads();   // stages dead; rings (aliased) live from here

  // ---------------- main pipelined loop ------------------------------------
  // opH/opL: wave0/1 = p frags (zero until loaded from sring); wave2/3 = u frags
  bf16x8 opH[2], opL[2];
  {
    bf16x8 z;
    #pragma unroll
    for (int j = 0; j < 8; ++j) z[j] = 0;
    opH[0] = z; opH[1] = z; opL[0] = z; opL[1] = z;
  }

  const float* ub = u + ((size_t)ln16 * kH + h) * kL + 8 * quad;
  float* yb = y + ((size_t)ln16 * kH + h) * kL;

  f32x4 uv[4];
  if (wid >= 2) {
    #pragma unroll
    for (int i = 0; i < 4; ++i)
      uv[i] = *(const f32x4*)(ub + 32 * (i >> 1) + 4 * (i & 1));
  }

  #pragma unroll 1
  for (int s = 0; s < kChunks + 2; ++s) {
    const int m3  = s % 3;                    // == (s-3)%3
    const int m3a = (m3 == 2) ? 0 : m3 + 1;   // == (s-2)%3
    const int m3b = (m3 == 0) ? 2 : m3 - 1;   // == (s-1)%3
    if (wid >= 2) {
      // ------- u-side: wave2 c_s = S·u -> cring; wave3 yu_s = G2S·u -> yuring
      if (s < kChunks) {
        cvt_split8(uv[0], uv[1], opH[0], opL[0]);
        cvt_split8(uv[2], uv[3], opH[1], opL[1]);
        const int tn = (s + 1 < kChunks) ? 64 * (s + 1) : 0;  // prefetch
        #pragma unroll
        for (int i = 0; i < 4; ++i)
          uv[i] = *(const f32x4*)(ub + tn + 32 * (i >> 1) + 4 * (i & 1));
        f32x4 acc[4] = {};
        #pragma unroll
        for (int mt = 0; mt < 4; ++mt) {
          #pragma unroll
          for (int tk = 0; tk < 2; ++tk) {
            acc[mt] = MFMA(oxH[mt][tk], opH[tk], acc[mt]);
            acc[mt] = MFMA(oxH[mt][tk], opL[tk], acc[mt]);
            acc[mt] = MFMA(oxL[mt][tk], opH[tk], acc[mt]);
          }
        }
        float* dst = (wid == 2) ? &cring[s & 1][0][0] : &yuring[m3][0][0];
        #pragma unroll
        for (int mt = 0; mt < 4; ++mt)
          *(f32x4*)&dst[ln16 * 68 + 16 * mt + 4 * quad] = acc[mt];
      }
    } else if (wid == 0) {
      // ------- state wave: r_{s-1} = A·p_{s-1} + c_{s-1} -> sring ----------
      if (s >= 1 && s <= kChunks) {
        if (s >= 2) {
          #pragma unroll
          for (int tk = 0; tk < 2; ++tk) {     // p_{s-1} = r_{s-2} @ sring[(s-2)%3]
            const int k0 = 8 * quad + 32 * tk;
            const f32x4 ra = *(const f32x4*)&sring[m3a][ln16][k0];
            const f32x4 rb = *(const f32x4*)&sring[m3a][ln16][k0 + 4];
            cvt_split8(ra, rb, opH[tk], opL[tk]);
          }
        }
        f32x4 acc[4];
        #pragma unroll
        for (int mt = 0; mt < 4; ++mt)
          acc[mt] = *(const f32x4*)&cring[(s - 1) & 1][ln16][16 * mt + 4 * quad];
        #pragma unroll
        for (int mt = 0; mt < 4; ++mt) {
          #pragma unroll
          for (int tk = 0; tk < 2; ++tk) {
            acc[mt] = MFMA(oxH[mt][tk], opH[tk], acc[mt]);
            acc[mt] = MFMA(oxH[mt][tk], opL[tk], acc[mt]);
            acc[mt] = MFMA(oxL[mt][tk], opH[tk], acc[mt]);
          }
        }
        #pragma unroll
        for (int mt = 0; mt < 4; ++mt)
          *(f32x4*)&sring[m3b][ln16][16 * mt + 4 * quad] = acc[mt];
      }
    } else {
      // ------- y wave: y_{s-2} = G'·p_{s-2} + yu_{s-2} -> global -----------
      if (s >= 2) {
        if (s >= 3) {
          #pragma unroll
          for (int tk = 0; tk < 2; ++tk) {     // p_{s-2} = r_{s-3} @ sring[(s-3)%3]
            const int k0 = 8 * quad + 32 * tk;
            const f32x4 ra = *(const f32x4*)&sring[m3][ln16][k0];
            const f32x4 rb = *(const f32x4*)&sring[m3][ln16][k0 + 4];
            cvt_split8(ra, rb, opH[tk], opL[tk]);
          }
        }
        f32x4 acc[4];
        #pragma unroll
        for (int mt = 0; mt < 4; ++mt)
          acc[mt] = *(const f32x4*)&yuring[m3a][ln16][16 * mt + 4 * quad];
        #pragma unroll
        for (int mt = 0; mt < 4; ++mt) {
          #pragma unroll
          for (int tk = 0; tk < 2; ++tk) {
            acc[mt] = MFMA(oxH[mt][tk], opH[tk], acc[mt]);
            acc[mt] = MFMA(oxH[mt][tk], opL[tk], acc[mt]);
            acc[mt] = MFMA(oxL[mt][tk], opH[tk], acc[mt]);
          }
        }
        #pragma unroll
        for (int mt = 0; mt < 4; ++mt)
          *(f32x4*)(yb + 64 * (s - 2) + 16 * mt + 4 * quad) = acc[mt];
      }
    }
    // step barrier: drain LDS only; u loads / y stores stay in flight
    asm volatile("s_waitcnt lgkmcnt(0)" ::: "memory");
    __builtin_amdgcn_s_barrier();
    asm volatile("" ::: "memory");
  }
}

}  // namespace

extern "C" void kernel_launch(void* const* d_in, const int* in_sizes, int n_in,
                              void* d_out, int out_size, void* d_ws, size_t ws_size,
                              hipStream_t stream) {
  const float* u  = (const float*)d_in[0];   // (16, 512, 2048) fp32
  const float* kk = (const float*)d_in[1];   // (1, 512, 64)    fp32
  if (n_in >= 2 && in_sizes[0] < in_sizes[1]) {
    const float* t = u; u = kk; kk = t;
  }
  float* yy = (float*)d_out;                 // (16, 512, 2048) fp32
  hipLaunchKernelGGL(ssm_mfma_kernel, dim3(kH), dim3(256), 0, stream, u, kk, yy);
}